// Round 6
// baseline (266.271 us; speedup 1.0000x reference)
//
#include <hip/hip_runtime.h>
#include <hip/hip_bf16.h>

#define T_TOKENS 8192
#define H_DIM    1024

typedef __bf16 bf16x8 __attribute__((ext_vector_type(8)));
typedef float  f32x4  __attribute__((ext_vector_type(4)));

__device__ __forceinline__ unsigned short f2bf(float f) {
    union { float f; unsigned u; } v; v.f = f;
    unsigned r = v.u + 0x7FFFu + ((v.u >> 16) & 1u);
    return (unsigned short)(r >> 16);
}
__device__ __forceinline__ float bflo(unsigned w) { union { unsigned u; float f; } v; v.u = w << 16; return v.f; }
__device__ __forceinline__ float bfhi(unsigned w) { union { unsigned u; float f; } v; v.u = w & 0xFFFF0000u; return v.f; }

__device__ __forceinline__ void gload_lds16(const unsigned short* g, unsigned short* l) {
    __builtin_amdgcn_global_load_lds(
        (const __attribute__((address_space(1))) unsigned int*)g,
        (__attribute__((address_space(3))) unsigned int*)l, 16, 0, 0);
}

#define VMCNT(n) asm volatile("s_waitcnt vmcnt(" #n ")" ::: "memory")
#define BARR()   __builtin_amdgcn_s_barrier()
#define PRIO1    __builtin_amdgcn_s_setprio(1)
#define PRIO0    __builtin_amdgcn_s_setprio(0)

// ---------------- fused pre: wconv (bids 0..8191) + router w/ atomic scatter (bids 8192..10239) ----------------
__global__ __launch_bounds__(256) void moe_pre(
    const float* __restrict__ x, const float* __restrict__ gw, const float* __restrict__ gb,
    const float* __restrict__ ew,
    float* __restrict__ logits, unsigned short* __restrict__ xb, unsigned short* __restrict__ wt,
    float* __restrict__ rp, int* __restrict__ ppos, int* __restrict__ tlist, int* __restrict__ cnt)
{
    __shared__ float smem[H_DIM * 9];
    int bid = blockIdx.x, tid = threadIdx.x;

    if (bid < 8192) {
        // ---- W transpose + bf16: Wt[e][n][k] = W[e][k][n], 32x32 tile ----
        int e = bid >> 10, rem = bid & 1023;
        int n0 = (rem & 31) << 5, k0 = (rem >> 5) << 5;
        int tx = tid & 31, ty = tid >> 5;
        const float* src = ew + ((size_t)e << 20) + (size_t)k0 * H_DIM + n0;
        #pragma unroll
        for (int i = 0; i < 4; ++i) smem[(ty + i*8) * 33 + tx] = src[(ty + i*8) * H_DIM + tx];
        __syncthreads();
        unsigned short* dst = wt + ((size_t)e << 20) + (size_t)n0 * H_DIM + k0;
        #pragma unroll
        for (int i = 0; i < 4; ++i) dst[(ty + i*8) * H_DIM + tx] = f2bf(smem[tx * 33 + ty + i*8]);
        return;
    }

    // ---- router: f32 logits, top-2, bf16 x, inline atomic scatter ----
    int rb = bid - 8192;
    for (int i = tid; i < H_DIM; i += 256) {
        const float* s = gw + i * 8;
        float* d = smem + i * 9;
        #pragma unroll
        for (int e = 0; e < 8; ++e) d[e] = s[e];
    }
    __syncthreads();

    int wave = tid >> 6, lane = tid & 63;
    int t = rb * 4 + wave;

    float xl[16];
    const float* xrow = x + (size_t)t * H_DIM;
    #pragma unroll
    for (int q = 0; q < 16; ++q) xl[q] = xrow[lane + 64 * q];

    float acc[8] = {0,0,0,0,0,0,0,0};
    #pragma unroll
    for (int q = 0; q < 16; ++q) {
        float xv = xl[q];
        const float* g = &smem[(lane + 64 * q) * 9];
        #pragma unroll
        for (int e = 0; e < 8; ++e) acc[e] += xv * g[e];
    }
    #pragma unroll
    for (int e = 0; e < 8; ++e) {
        float v = acc[e];
        #pragma unroll
        for (int m = 32; m >= 1; m >>= 1) v += __shfl_xor(v, m, 64);
        acc[e] = v + gb[e];
    }
    if (lane == 0) {
        float* lrow = logits + (size_t)t * 8;
        #pragma unroll
        for (int e = 0; e < 8; ++e) lrow[e] = acc[e];
        int b0 = 0; float v0 = acc[0];
        #pragma unroll
        for (int e = 1; e < 8; ++e) if (acc[e] > v0) { v0 = acc[e]; b0 = e; }
        int b1 = -1; float v1 = -1e30f;
        #pragma unroll
        for (int e = 0; e < 8; ++e) if (e != b0 && acc[e] > v1) { v1 = acc[e]; b1 = e; }
        float ex = __expf(v1 - v0);
        float s = 1.0f / (1.0f + ex);
        int p0 = atomicAdd(&cnt[b0], 1);
        int p1 = atomicAdd(&cnt[b1], 1);
        tlist[(b0 << 13) + p0] = t;
        tlist[(b1 << 13) + p1] = t;
        ppos[2*t]   = (b0 << 13) | p0;
        ppos[2*t+1] = (b1 << 13) | p1;
        rp[2*t] = s; rp[2*t+1] = ex * s;
    }
    unsigned short* xbrow = xb + (size_t)t * H_DIM;
    #pragma unroll
    for (int q = 0; q < 16; ++q) xbrow[lane + 64 * q] = f2bf(xl[q]);
}

// ---------------- grouped expert GEMM ----------------
// Main: 256x256x64, 8 waves, 4-phase counted-vmcnt, one round (<=256 tiles).
// Tail: 64x256x64 strips for per-expert remainder rows (<=128 tiles).
// Prefix tables computed per-thread from cnt[8] (fully unrolled, register-only).
__global__ __launch_bounds__(512, 2) void moe_gemm(
    const unsigned short* __restrict__ xb, const unsigned short* __restrict__ wt,
    const int* __restrict__ cntg, const int* __restrict__ tlist, unsigned short* __restrict__ eout)
{
    __shared__ __align__(16) unsigned short lds[65536];

    int bid = blockIdx.x;
    int tid = threadIdx.x;
    int wv = tid >> 6, lane = tid & 63;
    int lane15 = lane & 15, q = lane >> 4, l7 = lane & 7;
    int c00 = ((q)     ^ l7) << 3;
    int c01 = ((4 + q) ^ l7) << 3;

    int cc[8];
    #pragma unroll
    for (int i = 0; i < 8; ++i) cc[i] = cntg[i];
    int totMB = 0;
    #pragma unroll
    for (int i = 0; i < 8; ++i) totMB += cc[i] >> 8;
    int nmain = totMB << 2;

    if (bid < nmain) {
        // -------- main: 256x256 --------
        int w0;
        if (nmain >= 8) {           // bijective XCD chunk swizzle (m204)
            int qq = nmain >> 3, r = nmain & 7;
            int xq = bid & 7, o = bid >> 3;
            w0 = (xq < r ? xq * (qq + 1) : r * (qq + 1) + (xq - r) * qq) + o;
        } else w0 = bid;
        int mb_lin = w0 >> 2, nb = w0 & 3;

        int e = 0, off = 0, cnt = 0, mbSel = 0;
        {
            int offR = 0, mbb = 0;
            #pragma unroll
            for (int i = 0; i < 8; ++i) {
                int fl = cc[i] >> 8;
                if (mb_lin >= mbb && mb_lin < mbb + fl) { e = i; off = offR; cnt = cc[i]; mbSel = mbb; }
                mbb += fl; offR += cc[i];
            }
        }
        int m0 = (mb_lin - mbSel) << 8;
        int n0 = nb << 8;
        int wm = wv >> 2, wn = wv & 3;

        const unsigned short* wte = wt + ((size_t)e << 20);
        const int* tle = tlist + (e << 13);

        const unsigned short* aP[2][2];
        const unsigned short* bP[2];
        int dA[2], dB[2];
        #pragma unroll
        for (int l = 0; l < 2; ++l) {
            int c = wv * 128 + l * 64 + lane;
            int r = c >> 3, s = c & 7;
            int col = (s ^ (r & 7)) << 3;
            int rowA = (r & 63) + ((r >> 6) << 7);
            int rowB = ((r >> 5) << 6) + (r & 31);
            dA[l] = rowA * 64 + s * 8;
            dB[l] = rowB * 64 + s * 8;
            int ma = m0 + rowA, mb2 = ma + 64;
            int t0 = tle[ma  < cnt ? ma  : cnt - 1];
            int t1 = tle[mb2 < cnt ? mb2 : cnt - 1];
            aP[l][0] = xb + (size_t)t0 * H_DIM + col;
            aP[l][1] = xb + (size_t)t1 * H_DIM + col;
            bP[l] = wte + (size_t)(n0 + rowB) * H_DIM + col;
        }

        unsigned short* A_ = lds;
        unsigned short* B_ = lds + 32768;

#define STG_A(MH, TT, NXT) do { \
    gload_lds16(aP[0][MH] + (TT)*64, A_ + (NXT)*16384 + dA[0] + (MH)*4096); \
    gload_lds16(aP[1][MH] + (TT)*64, A_ + (NXT)*16384 + dA[1] + (MH)*4096); } while(0)
#define STG_B(NH, TT, NXT) do { \
    gload_lds16(bP[0] + (NH)*32768 + (TT)*64, B_ + (NXT)*16384 + dB[0] + (NH)*2048); \
    gload_lds16(bP[1] + (NH)*32768 + (TT)*64, B_ + (NXT)*16384 + dB[1] + (NH)*2048); } while(0)

        const unsigned short* aR = A_ + (wm * 128 + lane15) * 64;
        const unsigned short* bR = B_ + (wn * 64 + lane15) * 64;

#define READ_A(MH, CU) do { _Pragma("unroll") \
    for (int iq = 0; iq < 4; ++iq) { \
        a[iq][0] = *(const bf16x8*)(aR + (CU)*16384 + (MH)*4096 + iq*1024 + c00); \
        a[iq][1] = *(const bf16x8*)(aR + (CU)*16384 + (MH)*4096 + iq*1024 + c01); } } while(0)
#define READ_B(NH, CU) do { _Pragma("unroll") \
    for (int jj = 0; jj < 2; ++jj) { \
        b[(NH)*2+jj][0] = *(const bf16x8*)(bR + (CU)*16384 + (NH)*2048 + jj*1024 + c00); \
        b[(NH)*2+jj][1] = *(const bf16x8*)(bR + (CU)*16384 + (NH)*2048 + jj*1024 + c01); } } while(0)

        f32x4 acc[8][4];
        #pragma unroll
        for (int i = 0; i < 8; ++i)
            #pragma unroll
            for (int j = 0; j < 4; ++j) acc[i][j] = (f32x4){0.f,0.f,0.f,0.f};

#define MM(MH, NH) do { _Pragma("unroll") \
    for (int iq = 0; iq < 4; ++iq) { _Pragma("unroll") \
        for (int jj = 0; jj < 2; ++jj) { \
            acc[(MH)*4+iq][(NH)*2+jj] = __builtin_amdgcn_mfma_f32_16x16x32_bf16(a[iq][0], b[(NH)*2+jj][0], acc[(MH)*4+iq][(NH)*2+jj], 0,0,0); \
            acc[(MH)*4+iq][(NH)*2+jj] = __builtin_amdgcn_mfma_f32_16x16x32_bf16(a[iq][1], b[(NH)*2+jj][1], acc[(MH)*4+iq][(NH)*2+jj], 0,0,0); } } } while(0)

        STG_A(0, 0, 0); STG_B(0, 0, 0); STG_B(1, 0, 0); STG_A(1, 0, 0);
        VMCNT(4);
        BARR();

        for (int t = 0; t < 15; ++t) {
            int cu = t & 1, nx = cu ^ 1, tn = t + 1;
            bf16x8 a[4][2]; bf16x8 b[4][2];
            READ_A(0, cu); READ_B(0, cu);
            STG_A(0, tn, nx);
            BARR(); PRIO1; MM(0, 0); PRIO0; VMCNT(4); BARR();
            READ_B(1, cu);
            STG_B(0, tn, nx);
            BARR(); PRIO1; MM(0, 1); PRIO0; VMCNT(4); BARR();
            READ_A(1, cu);
            STG_B(1, tn, nx);
            BARR(); PRIO1; MM(1, 1); PRIO0; BARR();
            STG_A(1, tn, nx);
            BARR(); PRIO1; MM(1, 0); PRIO0; VMCNT(4); BARR();
        }
        {
            bf16x8 a[4][2]; bf16x8 b[4][2];
            READ_A(0, 1); READ_B(0, 1);
            BARR(); PRIO1; MM(0, 0); PRIO0; VMCNT(2); BARR();
            READ_B(1, 1);
            BARR(); PRIO1; MM(0, 1); PRIO0; VMCNT(0); BARR();
            READ_A(1, 1);
            BARR(); PRIO1; MM(1, 1); PRIO0; BARR();
            PRIO1; MM(1, 0); PRIO0;
        }

        #pragma unroll
        for (int i = 0; i < 8; ++i) {
            #pragma unroll
            for (int rr = 0; rr < 4; ++rr) {
                int m = m0 + wm * 128 + i * 16 + (q << 2) + rr;
                if (m < cnt) {
                    unsigned short* erow = eout + (size_t)(off + m) * H_DIM + n0 + wn * 64 + lane15;
                    #pragma unroll
                    for (int j = 0; j < 4; ++j)
                        erow[j * 16] = f2bf(acc[i][j][rr]);
                }
            }
        }
        return;
#undef STG_A
#undef STG_B
#undef READ_A
#undef READ_B
#undef MM
    }

    // -------- tail: 64x256 strips over remainder rows --------
    int w1 = bid - nmain;
    int totTB = 0;
    #pragma unroll
    for (int i = 0; i < 8; ++i) { int fl = cc[i] >> 8; totTB += ((cc[i] - (fl << 8)) + 63) >> 6; }
    if (w1 >= totTB * 4) return;
    int s_lin = w1 >> 2, nb = w1 & 3;

    int e = 0, off = 0, cnt = 0, tbSel = 0, flSel = 0;
    {
        int offR = 0, tbb = 0;
        #pragma unroll
        for (int i = 0; i < 8; ++i) {
            int fl = cc[i] >> 8;
            int ts = ((cc[i] - (fl << 8)) + 63) >> 6;
            if (s_lin >= tbb && s_lin < tbb + ts) { e = i; off = offR; cnt = cc[i]; tbSel = tbb; flSel = fl; }
            tbb += ts; offR += cc[i];
        }
    }
    int m0 = (flSel << 8) + ((s_lin - tbSel) << 6);
    int n0 = nb << 8;
    int wm2 = wv >> 2, wn = wv & 3;

    const unsigned short* wte = wt + ((size_t)e << 20);
    const int* tle = tlist + (e << 13);

    int rA = tid >> 3, sA = tid & 7;
    int colA = (sA ^ (rA & 7)) << 3;
    int ma = m0 + rA;
    const unsigned short* aP = xb + (size_t)tle[ma < cnt ? ma : cnt - 1] * H_DIM + colA;
    int dAt = rA * 64 + sA * 8;

    const unsigned short* bP[2];
    int dB[2];
    #pragma unroll
    for (int l = 0; l < 2; ++l) {
        int c = wv * 128 + l * 64 + lane;
        int r = c >> 3, s = c & 7;
        int col = (s ^ (r & 7)) << 3;
        int rowB = ((r >> 5) << 6) + (r & 31);
        dB[l] = rowB * 64 + s * 8;
        bP[l] = wte + (size_t)(n0 + rowB) * H_DIM + col;
    }

    unsigned short* A_ = lds;
    unsigned short* B_ = lds + 8192;

    const unsigned short* aR = A_ + (wm2 * 32 + lane15) * 64;
    const unsigned short* bR = B_ + (wn * 64 + lane15) * 64;

#define TSTG_A(TT, NXT) gload_lds16(aP + (TT)*64, A_ + (NXT)*4096 + dAt)
#define TSTG_B(NH, TT, NXT) do { \
    gload_lds16(bP[0] + (NH)*32768 + (TT)*64, B_ + (NXT)*16384 + dB[0] + (NH)*2048); \
    gload_lds16(bP[1] + (NH)*32768 + (TT)*64, B_ + (NXT)*16384 + dB[1] + (NH)*2048); } while(0)
#define TREAD_A(CU) do { _Pragma("unroll") \
    for (int iq = 0; iq < 2; ++iq) { \
        a[iq][0] = *(const bf16x8*)(aR + (CU)*4096 + iq*1024 + c00); \
        a[iq][1] = *(const bf16x8*)(aR + (CU)*4096 + iq*1024 + c01); } } while(0)
#define TREAD_B(NH, CU) do { _Pragma("unroll") \
    for (int jj = 0; jj < 2; ++jj) { \
        b[(NH)*2+jj][0] = *(const bf16x8*)(bR + (CU)*16384 + (NH)*2048 + jj*1024 + c00); \
        b[(NH)*2+jj][1] = *(const bf16x8*)(bR + (CU)*16384 + (NH)*2048 + jj*1024 + c01); } } while(0)
#define TMM(NH) do { _Pragma("unroll") \
    for (int iq = 0; iq < 2; ++iq) { _Pragma("unroll") \
        for (int jj = 0; jj < 2; ++jj) { \
            acc[iq][(NH)*2+jj] = __builtin_amdgcn_mfma_f32_16x16x32_bf16(a[iq][0], b[(NH)*2+jj][0], acc[iq][(NH)*2+jj], 0,0,0); \
            acc[iq][(NH)*2+jj] = __builtin_amdgcn_mfma_f32_16x16x32_bf16(a[iq][1], b[(NH)*2+jj][1], acc[iq][(NH)*2+jj], 0,0,0); } } } while(0)

    f32x4 acc[2][4];
    #pragma unroll
    for (int i = 0; i < 2; ++i)
        #pragma unroll
        for (int j = 0; j < 4; ++j) acc[i][j] = (f32x4){0.f,0.f,0.f,0.f};

    TSTG_A(0, 0); TSTG_B(0, 0, 0); TSTG_B(1, 0, 0);
    VMCNT(2); BARR();

    for (int t = 0; t < 15; ++t) {
        int cu = t & 1, nx = cu ^ 1, tn = t + 1;
        bf16x8 a[2][2]; bf16x8 b[4][2];
        TREAD_A(cu); TREAD_B(0, cu);
        TSTG_A(tn, nx); TSTG_B(0, tn, nx);
        BARR(); PRIO1; TMM(0); PRIO0; VMCNT(3); BARR();
        TREAD_B(1, cu);
        TSTG_B(1, tn, nx);
        BARR(); PRIO1; TMM(1); PRIO0; VMCNT(2); BARR();
    }
    {
        bf16x8 a[2][2]; bf16x8 b[4][2];
        TREAD_A(1); TREAD_B(0, 1);
        BARR(); PRIO1; TMM(0); PRIO0; VMCNT(0); BARR();
        TREAD_B(1, 1);
        BARR(); PRIO1; TMM(1); PRIO0;
    }

    #pragma unroll
    for (int iq = 0; iq < 2; ++iq) {
        #pragma unroll
        for (int rr = 0; rr < 4; ++rr) {
            int m = m0 + wm2 * 32 + iq * 16 + (q << 2) + rr;
            if (m < cnt) {
                unsigned short* erow = eout + (size_t)(off + m) * H_DIM + n0 + wn * 64 + lane15;
                #pragma unroll
                for (int j = 0; j < 4; ++j)
                    erow[j * 16] = f2bf(acc[iq][j][rr]);
            }
        }
    }
#undef TSTG_A
#undef TSTG_B
#undef TREAD_A
#undef TREAD_B
#undef TMM
}

// ---------------- combine: out[t] = p0*(v0 + b_e0) + p1*(v1 + b_e1) ----------------
__global__ __launch_bounds__(256) void moe_combine(
    const float* __restrict__ rp, const int* __restrict__ ppos, const int* __restrict__ cntg,
    const unsigned short* __restrict__ eout, const float* __restrict__ eb, float* __restrict__ out)
{
    __shared__ int offsS[8];
    if (threadIdx.x == 0) {
        int s = 0;
        #pragma unroll
        for (int i = 0; i < 8; ++i) { offsS[i] = s; s += cntg[i]; }
    }
    __syncthreads();
    int idx = blockIdx.x * 256 + threadIdx.x;
    int t = idx >> 7, c = (idx & 127) << 3;
    int u0 = ppos[2*t], u1 = ppos[2*t+1];
    int e0 = u0 >> 13, e1 = u1 >> 13;
    int s0 = offsS[e0] + (u0 & 8191);
    int s1 = offsS[e1] + (u1 & 8191);
    float p0 = rp[2*t], p1 = rp[2*t+1];
    uint4 v0 = *(const uint4*)(eout + (size_t)s0 * H_DIM + c);
    uint4 v1 = *(const uint4*)(eout + (size_t)s1 * H_DIM + c);
    const float* b0 = eb + e0 * H_DIM + c;
    const float* b1 = eb + e1 * H_DIM + c;
    float r[8];
    const unsigned* w0 = &v0.x;
    const unsigned* w1 = &v1.x;
    #pragma unroll
    for (int k = 0; k < 4; ++k) {
        r[2*k]   = p0 * (bflo(w0[k]) + b0[2*k])   + p1 * (bflo(w1[k]) + b1[2*k]);
        r[2*k+1] = p0 * (bfhi(w0[k]) + b0[2*k+1]) + p1 * (bfhi(w1[k]) + b1[2*k+1]);
    }
    float4* op = (float4*)(out + (size_t)t * H_DIM + c);
    op[0] = make_float4(r[0], r[1], r[2], r[3]);
    op[1] = make_float4(r[4], r[5], r[6], r[7]);
}

extern "C" void kernel_launch(void* const* d_in, const int* in_sizes, int n_in,
                              void* d_out, int out_size, void* d_ws, size_t ws_size,
                              hipStream_t stream) {
    const float* x  = (const float*)d_in[0];
    const float* gw = (const float*)d_in[1];
    const float* gb = (const float*)d_in[2];
    const float* ew = (const float*)d_in[3];
    const float* eb = (const float*)d_in[4];

    float* out    = (float*)d_out;
    float* logits = out + (size_t)T_TOKENS * H_DIM;

    char* ws = (char*)d_ws;
    unsigned short* xb   = (unsigned short*)(ws);                       // 16 MiB
    unsigned short* wt   = (unsigned short*)(ws + 16777216);            // 16 MiB
    unsigned short* eout = (unsigned short*)(ws + 33554432);            // 32 MiB
    int*   tlist   = (int*)  (ws + 67108864);                           // 256 KiB (8 x 8192)
    float* rp      = (float*)(ws + 67371008);                           // 64 KiB
    int*   ppos    = (int*)  (ws + 67436544);                           // 64 KiB
    int*   cnt     = (int*)  (ws + 67502080);                           // 8 ints

    hipMemsetAsync(cnt, 0, 32, stream);

    moe_pre    <<<10240, 256, 0, stream>>>(x, gw, gb, ew, logits, xb, wt, rp, ppos, tlist, cnt);
    moe_gemm   <<<384, 512, 0, stream>>>(xb, wt, cnt, tlist, eout);
    moe_combine<<<(T_TOKENS*H_DIM/8)/256, 256, 0, stream>>>(rp, ppos, cnt, eout, eb, out);
}

// Round 7
// 128.565 us; speedup vs baseline: 2.0711x; 2.0711x over previous
//
#include <hip/hip_runtime.h>
#include <hip/hip_bf16.h>

#define T_TOKENS 8192
#define H_DIM    1024

typedef __bf16 bf16x8 __attribute__((ext_vector_type(8)));
typedef float  f32x4  __attribute__((ext_vector_type(4)));

__device__ __forceinline__ unsigned short f2bf(float f) {
    union { float f; unsigned u; } v; v.f = f;
    unsigned r = v.u + 0x7FFFu + ((v.u >> 16) & 1u);
    return (unsigned short)(r >> 16);
}
__device__ __forceinline__ float bflo(unsigned w) { union { unsigned u; float f; } v; v.u = w << 16; return v.f; }
__device__ __forceinline__ float bfhi(unsigned w) { union { unsigned u; float f; } v; v.u = w & 0xFFFF0000u; return v.f; }

__device__ __forceinline__ void gload_lds16(const unsigned short* g, unsigned short* l) {
    __builtin_amdgcn_global_load_lds(
        (const __attribute__((address_space(1))) unsigned int*)g,
        (__attribute__((address_space(3))) unsigned int*)l, 16, 0, 0);
}

#define VMCNT(n) asm volatile("s_waitcnt vmcnt(" #n ")" ::: "memory")
#define BARR()   __builtin_amdgcn_s_barrier()
#define PRIO1    __builtin_amdgcn_s_setprio(1)
#define PRIO0    __builtin_amdgcn_s_setprio(0)

// ---------------- fused pre: wconv (bids 0..8191) + router (bids 8192..8255, 128 tok/block) ----------------
// Router scatter: LDS histogram -> 8 wave-coalesced global atomics per block (64 blocks total).
// Never O(tokens) same-line global RMWs (R6 lesson: 16K serialized atomics = 200us).
__global__ __launch_bounds__(256) void moe_pre(
    const float* __restrict__ x, const float* __restrict__ gw, const float* __restrict__ gb,
    const float* __restrict__ ew,
    float* __restrict__ logits, unsigned short* __restrict__ xb, unsigned short* __restrict__ wt,
    float* __restrict__ rp, int* __restrict__ ppos, int* __restrict__ tlist, int* __restrict__ cnt)
{
    __shared__ float smem[H_DIM * 9];     // gate weights padded / wconv tile
    __shared__ int   e0s[128], e1s[128];
    __shared__ int   hist[8], baseS[8];
    int bid = blockIdx.x, tid = threadIdx.x;

    if (bid < 8192) {
        // ---- W transpose + bf16: Wt[e][n][k] = W[e][k][n], 32x32 tile ----
        int e = bid >> 10, rem = bid & 1023;
        int n0 = (rem & 31) << 5, k0 = (rem >> 5) << 5;
        int tx = tid & 31, ty = tid >> 5;
        const float* src = ew + ((size_t)e << 20) + (size_t)k0 * H_DIM + n0;
        #pragma unroll
        for (int i = 0; i < 4; ++i) smem[(ty + i*8) * 33 + tx] = src[(ty + i*8) * H_DIM + tx];
        __syncthreads();
        unsigned short* dst = wt + ((size_t)e << 20) + (size_t)n0 * H_DIM + k0;
        #pragma unroll
        for (int i = 0; i < 4; ++i) dst[(ty + i*8) * H_DIM + tx] = f2bf(smem[tx * 33 + ty + i*8]);
        return;
    }

    // ---- router: f32 logits, top-2, bf16 x ----
    int rb = bid - 8192;                  // 0..63
    if (tid < 8) hist[tid] = 0;
    for (int i = tid; i < H_DIM; i += 256) {
        const float* s = gw + i * 8;
        float* d = smem + i * 9;
        #pragma unroll
        for (int e = 0; e < 8; ++e) d[e] = s[e];
    }
    __syncthreads();

    int wave = tid >> 6, lane = tid & 63;

    for (int it = 0; it < 32; ++it) {
        int tl = wave * 32 + it;          // local token 0..127
        int t = rb * 128 + tl;

        float xl[16];
        const float* xrow = x + (size_t)t * H_DIM;
        #pragma unroll
        for (int q = 0; q < 16; ++q) xl[q] = xrow[lane + 64 * q];

        float acc[8] = {0,0,0,0,0,0,0,0};
        #pragma unroll
        for (int q = 0; q < 16; ++q) {
            float xv = xl[q];
            const float* g = &smem[(lane + 64 * q) * 9];
            #pragma unroll
            for (int e = 0; e < 8; ++e) acc[e] += xv * g[e];
        }
        #pragma unroll
        for (int e = 0; e < 8; ++e) {
            float v = acc[e];
            #pragma unroll
            for (int m = 32; m >= 1; m >>= 1) v += __shfl_xor(v, m, 64);
            acc[e] = v + gb[e];
        }
        if (lane == 0) {
            float* lrow = logits + (size_t)t * 8;
            #pragma unroll
            for (int e = 0; e < 8; ++e) lrow[e] = acc[e];
            int b0 = 0; float v0 = acc[0];
            #pragma unroll
            for (int e = 1; e < 8; ++e) if (acc[e] > v0) { v0 = acc[e]; b0 = e; }
            int b1 = -1; float v1 = -1e30f;
            #pragma unroll
            for (int e = 0; e < 8; ++e) if (e != b0 && acc[e] > v1) { v1 = acc[e]; b1 = e; }
            float ex = __expf(v1 - v0);
            float s = 1.0f / (1.0f + ex);
            e0s[tl] = b0; e1s[tl] = b1;
            rp[2*t] = s;  rp[2*t+1] = ex * s;
        }
        unsigned short* xbrow = xb + (size_t)t * H_DIM;
        #pragma unroll
        for (int q = 0; q < 16; ++q) xbrow[lane + 64 * q] = f2bf(xl[q]);
    }
    __syncthreads();

    // block-level scatter: thread -> (token tid>>1, slot tid&1)
    int tl = tid >> 1, slot = tid & 1;
    int e = slot ? e1s[tl] : e0s[tl];
    int l = atomicAdd(&hist[e], 1);       // LDS atomic: local position
    __syncthreads();
    if (tid < 8 && hist[tid]) baseS[tid] = atomicAdd(&cnt[tid], hist[tid]);
    __syncthreads();
    int t = rb * 128 + tl;
    int pos = baseS[e] + l;
    tlist[(e << 13) + pos] = t;
    ppos[2*t + slot] = (e << 13) | pos;
}

// ---------------- grouped expert GEMM ----------------
// Main: 256x256x64, 8 waves, 4-phase counted-vmcnt, one round (<=256 tiles).
// Tail: 64x256x64 strips for per-expert remainder rows (<=128 tiles).
__global__ __launch_bounds__(512, 2) void moe_gemm(
    const unsigned short* __restrict__ xb, const unsigned short* __restrict__ wt,
    const int* __restrict__ cntg, const int* __restrict__ tlist, unsigned short* __restrict__ eout)
{
    __shared__ __align__(16) unsigned short lds[65536];

    int bid = blockIdx.x;
    int tid = threadIdx.x;
    int wv = tid >> 6, lane = tid & 63;
    int lane15 = lane & 15, q = lane >> 4, l7 = lane & 7;
    int c00 = ((q)     ^ l7) << 3;
    int c01 = ((4 + q) ^ l7) << 3;

    int cc[8];
    #pragma unroll
    for (int i = 0; i < 8; ++i) cc[i] = cntg[i];
    int totMB = 0;
    #pragma unroll
    for (int i = 0; i < 8; ++i) totMB += cc[i] >> 8;
    int nmain = totMB << 2;

    if (bid < nmain) {
        // -------- main: 256x256 --------
        int w0;
        if (nmain >= 8) {           // bijective XCD chunk swizzle (m204)
            int qq = nmain >> 3, r = nmain & 7;
            int xq = bid & 7, o = bid >> 3;
            w0 = (xq < r ? xq * (qq + 1) : r * (qq + 1) + (xq - r) * qq) + o;
        } else w0 = bid;
        int mb_lin = w0 >> 2, nb = w0 & 3;

        int e = 0, off = 0, cnt = 0, mbSel = 0;
        {
            int offR = 0, mbb = 0;
            #pragma unroll
            for (int i = 0; i < 8; ++i) {
                int fl = cc[i] >> 8;
                if (mb_lin >= mbb && mb_lin < mbb + fl) { e = i; off = offR; cnt = cc[i]; mbSel = mbb; }
                mbb += fl; offR += cc[i];
            }
        }
        int m0 = (mb_lin - mbSel) << 8;
        int n0 = nb << 8;
        int wm = wv >> 2, wn = wv & 3;

        const unsigned short* wte = wt + ((size_t)e << 20);
        const int* tle = tlist + (e << 13);

        const unsigned short* aP[2][2];
        const unsigned short* bP[2];
        int dA[2], dB[2];
        #pragma unroll
        for (int l = 0; l < 2; ++l) {
            int c = wv * 128 + l * 64 + lane;
            int r = c >> 3, s = c & 7;
            int col = (s ^ (r & 7)) << 3;
            int rowA = (r & 63) + ((r >> 6) << 7);
            int rowB = ((r >> 5) << 6) + (r & 31);
            dA[l] = rowA * 64 + s * 8;
            dB[l] = rowB * 64 + s * 8;
            int ma = m0 + rowA, mb2 = ma + 64;
            int t0 = tle[ma  < cnt ? ma  : cnt - 1];
            int t1 = tle[mb2 < cnt ? mb2 : cnt - 1];
            aP[l][0] = xb + (size_t)t0 * H_DIM + col;
            aP[l][1] = xb + (size_t)t1 * H_DIM + col;
            bP[l] = wte + (size_t)(n0 + rowB) * H_DIM + col;
        }

        unsigned short* A_ = lds;
        unsigned short* B_ = lds + 32768;

#define STG_A(MH, TT, NXT) do { \
    gload_lds16(aP[0][MH] + (TT)*64, A_ + (NXT)*16384 + dA[0] + (MH)*4096); \
    gload_lds16(aP[1][MH] + (TT)*64, A_ + (NXT)*16384 + dA[1] + (MH)*4096); } while(0)
#define STG_B(NH, TT, NXT) do { \
    gload_lds16(bP[0] + (NH)*32768 + (TT)*64, B_ + (NXT)*16384 + dB[0] + (NH)*2048); \
    gload_lds16(bP[1] + (NH)*32768 + (TT)*64, B_ + (NXT)*16384 + dB[1] + (NH)*2048); } while(0)

        const unsigned short* aR = A_ + (wm * 128 + lane15) * 64;
        const unsigned short* bR = B_ + (wn * 64 + lane15) * 64;

#define READ_A(MH, CU) do { _Pragma("unroll") \
    for (int iq = 0; iq < 4; ++iq) { \
        a[iq][0] = *(const bf16x8*)(aR + (CU)*16384 + (MH)*4096 + iq*1024 + c00); \
        a[iq][1] = *(const bf16x8*)(aR + (CU)*16384 + (MH)*4096 + iq*1024 + c01); } } while(0)
#define READ_B(NH, CU) do { _Pragma("unroll") \
    for (int jj = 0; jj < 2; ++jj) { \
        b[(NH)*2+jj][0] = *(const bf16x8*)(bR + (CU)*16384 + (NH)*2048 + jj*1024 + c00); \
        b[(NH)*2+jj][1] = *(const bf16x8*)(bR + (CU)*16384 + (NH)*2048 + jj*1024 + c01); } } while(0)

        f32x4 acc[8][4];
        #pragma unroll
        for (int i = 0; i < 8; ++i)
            #pragma unroll
            for (int j = 0; j < 4; ++j) acc[i][j] = (f32x4){0.f,0.f,0.f,0.f};

#define MM(MH, NH) do { _Pragma("unroll") \
    for (int iq = 0; iq < 4; ++iq) { _Pragma("unroll") \
        for (int jj = 0; jj < 2; ++jj) { \
            acc[(MH)*4+iq][(NH)*2+jj] = __builtin_amdgcn_mfma_f32_16x16x32_bf16(a[iq][0], b[(NH)*2+jj][0], acc[(MH)*4+iq][(NH)*2+jj], 0,0,0); \
            acc[(MH)*4+iq][(NH)*2+jj] = __builtin_amdgcn_mfma_f32_16x16x32_bf16(a[iq][1], b[(NH)*2+jj][1], acc[(MH)*4+iq][(NH)*2+jj], 0,0,0); } } } while(0)

        STG_A(0, 0, 0); STG_B(0, 0, 0); STG_B(1, 0, 0); STG_A(1, 0, 0);
        VMCNT(4);
        BARR();

        for (int t = 0; t < 15; ++t) {
            int cu = t & 1, nx = cu ^ 1, tn = t + 1;
            bf16x8 a[4][2]; bf16x8 b[4][2];
            READ_A(0, cu); READ_B(0, cu);
            STG_A(0, tn, nx);
            BARR(); PRIO1; MM(0, 0); PRIO0; VMCNT(4); BARR();
            READ_B(1, cu);
            STG_B(0, tn, nx);
            BARR(); PRIO1; MM(0, 1); PRIO0; VMCNT(4); BARR();
            READ_A(1, cu);
            STG_B(1, tn, nx);
            BARR(); PRIO1; MM(1, 1); PRIO0; BARR();
            STG_A(1, tn, nx);
            BARR(); PRIO1; MM(1, 0); PRIO0; VMCNT(4); BARR();
        }
        {
            bf16x8 a[4][2]; bf16x8 b[4][2];
            READ_A(0, 1); READ_B(0, 1);
            BARR(); PRIO1; MM(0, 0); PRIO0; VMCNT(2); BARR();
            READ_B(1, 1);
            BARR(); PRIO1; MM(0, 1); PRIO0; VMCNT(0); BARR();
            READ_A(1, 1);
            BARR(); PRIO1; MM(1, 1); PRIO0; BARR();
            PRIO1; MM(1, 0); PRIO0;
        }

        #pragma unroll
        for (int i = 0; i < 8; ++i) {
            #pragma unroll
            for (int rr = 0; rr < 4; ++rr) {
                int m = m0 + wm * 128 + i * 16 + (q << 2) + rr;
                if (m < cnt) {
                    unsigned short* erow = eout + (size_t)(off + m) * H_DIM + n0 + wn * 64 + lane15;
                    #pragma unroll
                    for (int j = 0; j < 4; ++j)
                        erow[j * 16] = f2bf(acc[i][j][rr]);
                }
            }
        }
        return;
#undef STG_A
#undef STG_B
#undef READ_A
#undef READ_B
#undef MM
    }

    // -------- tail: 64x256 strips over remainder rows --------
    int w1 = bid - nmain;
    int totTB = 0;
    #pragma unroll
    for (int i = 0; i < 8; ++i) { int fl = cc[i] >> 8; totTB += ((cc[i] - (fl << 8)) + 63) >> 6; }
    if (w1 >= totTB * 4) return;
    int s_lin = w1 >> 2, nb = w1 & 3;

    int e = 0, off = 0, cnt = 0, tbSel = 0, flSel = 0;
    {
        int offR = 0, tbb = 0;
        #pragma unroll
        for (int i = 0; i < 8; ++i) {
            int fl = cc[i] >> 8;
            int ts = ((cc[i] - (fl << 8)) + 63) >> 6;
            if (s_lin >= tbb && s_lin < tbb + ts) { e = i; off = offR; cnt = cc[i]; tbSel = tbb; flSel = fl; }
            tbb += ts; offR += cc[i];
        }
    }
    int m0 = (flSel << 8) + ((s_lin - tbSel) << 6);
    int n0 = nb << 8;
    int wm2 = wv >> 2, wn = wv & 3;

    const unsigned short* wte = wt + ((size_t)e << 20);
    const int* tle = tlist + (e << 13);

    int rA = tid >> 3, sA = tid & 7;
    int colA = (sA ^ (rA & 7)) << 3;
    int ma = m0 + rA;
    const unsigned short* aP = xb + (size_t)tle[ma < cnt ? ma : cnt - 1] * H_DIM + colA;
    int dAt = rA * 64 + sA * 8;

    const unsigned short* bP[2];
    int dB[2];
    #pragma unroll
    for (int l = 0; l < 2; ++l) {
        int c = wv * 128 + l * 64 + lane;
        int r = c >> 3, s = c & 7;
        int col = (s ^ (r & 7)) << 3;
        int rowB = ((r >> 5) << 6) + (r & 31);
        dB[l] = rowB * 64 + s * 8;
        bP[l] = wte + (size_t)(n0 + rowB) * H_DIM + col;
    }

    unsigned short* A_ = lds;
    unsigned short* B_ = lds + 8192;

    const unsigned short* aR = A_ + (wm2 * 32 + lane15) * 64;
    const unsigned short* bR = B_ + (wn * 64 + lane15) * 64;

#define TSTG_A(TT, NXT) gload_lds16(aP + (TT)*64, A_ + (NXT)*4096 + dAt)
#define TSTG_B(NH, TT, NXT) do { \
    gload_lds16(bP[0] + (NH)*32768 + (TT)*64, B_ + (NXT)*16384 + dB[0] + (NH)*2048); \
    gload_lds16(bP[1] + (NH)*32768 + (TT)*64, B_ + (NXT)*16384 + dB[1] + (NH)*2048); } while(0)
#define TREAD_A(CU) do { _Pragma("unroll") \
    for (int iq = 0; iq < 2; ++iq) { \
        a[iq][0] = *(const bf16x8*)(aR + (CU)*4096 + iq*1024 + c00); \
        a[iq][1] = *(const bf16x8*)(aR + (CU)*4096 + iq*1024 + c01); } } while(0)
#define TREAD_B(NH, CU) do { _Pragma("unroll") \
    for (int jj = 0; jj < 2; ++jj) { \
        b[(NH)*2+jj][0] = *(const bf16x8*)(bR + (CU)*16384 + (NH)*2048 + jj*1024 + c00); \
        b[(NH)*2+jj][1] = *(const bf16x8*)(bR + (CU)*16384 + (NH)*2048 + jj*1024 + c01); } } while(0)
#define TMM(NH) do { _Pragma("unroll") \
    for (int iq = 0; iq < 2; ++iq) { _Pragma("unroll") \
        for (int jj = 0; jj < 2; ++jj) { \
            acc[iq][(NH)*2+jj] = __builtin_amdgcn_mfma_f32_16x16x32_bf16(a[iq][0], b[(NH)*2+jj][0], acc[iq][(NH)*2+jj], 0,0,0); \
            acc[iq][(NH)*2+jj] = __builtin_amdgcn_mfma_f32_16x16x32_bf16(a[iq][1], b[(NH)*2+jj][1], acc[iq][(NH)*2+jj], 0,0,0); } } } while(0)

    f32x4 acc[2][4];
    #pragma unroll
    for (int i = 0; i < 2; ++i)
        #pragma unroll
        for (int j = 0; j < 4; ++j) acc[i][j] = (f32x4){0.f,0.f,0.f,0.f};

    TSTG_A(0, 0); TSTG_B(0, 0, 0); TSTG_B(1, 0, 0);
    VMCNT(2); BARR();

    for (int t = 0; t < 15; ++t) {
        int cu = t & 1, nx = cu ^ 1, tn = t + 1;
        bf16x8 a[2][2]; bf16x8 b[4][2];
        TREAD_A(cu); TREAD_B(0, cu);
        TSTG_A(tn, nx); TSTG_B(0, tn, nx);
        BARR(); PRIO1; TMM(0); PRIO0; VMCNT(3); BARR();
        TREAD_B(1, cu);
        TSTG_B(1, tn, nx);
        BARR(); PRIO1; TMM(1); PRIO0; VMCNT(2); BARR();
    }
    {
        bf16x8 a[2][2]; bf16x8 b[4][2];
        TREAD_A(1); TREAD_B(0, 1);
        BARR(); PRIO1; TMM(0); PRIO0; VMCNT(0); BARR();
        TREAD_B(1, 1);
        BARR(); PRIO1; TMM(1); PRIO0;
    }

    #pragma unroll
    for (int iq = 0; iq < 2; ++iq) {
        #pragma unroll
        for (int rr = 0; rr < 4; ++rr) {
            int m = m0 + wm2 * 32 + iq * 16 + (q << 2) + rr;
            if (m < cnt) {
                unsigned short* erow = eout + (size_t)(off + m) * H_DIM + n0 + wn * 64 + lane15;
                #pragma unroll
                for (int j = 0; j < 4; ++j)
                    erow[j * 16] = f2bf(acc[iq][j][rr]);
            }
        }
    }
#undef TSTG_A
#undef TSTG_B
#undef TREAD_A
#undef TREAD_B
#undef TMM
}

// ---------------- combine: out[t] = p0*(v0 + b_e0) + p1*(v1 + b_e1) ----------------
__global__ __launch_bounds__(256) void moe_combine(
    const float* __restrict__ rp, const int* __restrict__ ppos, const int* __restrict__ cntg,
    const unsigned short* __restrict__ eout, const float* __restrict__ eb, float* __restrict__ out)
{
    __shared__ int offsS[8];
    if (threadIdx.x == 0) {
        int s = 0;
        #pragma unroll
        for (int i = 0; i < 8; ++i) { offsS[i] = s; s += cntg[i]; }
    }
    __syncthreads();
    int idx = blockIdx.x * 256 + threadIdx.x;
    int t = idx >> 7, c = (idx & 127) << 3;
    int u0 = ppos[2*t], u1 = ppos[2*t+1];
    int e0 = u0 >> 13, e1 = u1 >> 13;
    int s0 = offsS[e0] + (u0 & 8191);
    int s1 = offsS[e1] + (u1 & 8191);
    float p0 = rp[2*t], p1 = rp[2*t+1];
    uint4 v0 = *(const uint4*)(eout + (size_t)s0 * H_DIM + c);
    uint4 v1 = *(const uint4*)(eout + (size_t)s1 * H_DIM + c);
    const float* b0 = eb + e0 * H_DIM + c;
    const float* b1 = eb + e1 * H_DIM + c;
    float r[8];
    const unsigned* w0 = &v0.x;
    const unsigned* w1 = &v1.x;
    #pragma unroll
    for (int k = 0; k < 4; ++k) {
        r[2*k]   = p0 * (bflo(w0[k]) + b0[2*k])   + p1 * (bflo(w1[k]) + b1[2*k]);
        r[2*k+1] = p0 * (bfhi(w0[k]) + b0[2*k+1]) + p1 * (bfhi(w1[k]) + b1[2*k+1]);
    }
    float4* op = (float4*)(out + (size_t)t * H_DIM + c);
    op[0] = make_float4(r[0], r[1], r[2], r[3]);
    op[1] = make_float4(r[4], r[5], r[6], r[7]);
}

extern "C" void kernel_launch(void* const* d_in, const int* in_sizes, int n_in,
                              void* d_out, int out_size, void* d_ws, size_t ws_size,
                              hipStream_t stream) {
    const float* x  = (const float*)d_in[0];
    const float* gw = (const float*)d_in[1];
    const float* gb = (const float*)d_in[2];
    const float* ew = (const float*)d_in[3];
    const float* eb = (const float*)d_in[4];

    float* out    = (float*)d_out;
    float* logits = out + (size_t)T_TOKENS * H_DIM;

    char* ws = (char*)d_ws;
    unsigned short* xb   = (unsigned short*)(ws);                       // 16 MiB
    unsigned short* wt   = (unsigned short*)(ws + 16777216);            // 16 MiB
    unsigned short* eout = (unsigned short*)(ws + 33554432);            // 32 MiB
    int*   tlist   = (int*)  (ws + 67108864);                           // 256 KiB (8 x 8192)
    float* rp      = (float*)(ws + 67371008);                           // 64 KiB
    int*   ppos    = (int*)  (ws + 67436544);                           // 64 KiB
    int*   cnt     = (int*)  (ws + 67502080);                           // 8 ints

    hipMemsetAsync(cnt, 0, 32, stream);

    moe_pre    <<<8256, 256, 0, stream>>>(x, gw, gb, ew, logits, xb, wt, rp, ppos, tlist, cnt);
    moe_gemm   <<<384, 512, 0, stream>>>(xb, wt, cnt, tlist, eout);
    moe_combine<<<(T_TOKENS*H_DIM/8)/256, 256, 0, stream>>>(rp, ppos, cnt, eout, eb, out);
}

// Round 8
// 83.706 us; speedup vs baseline: 3.1810x; 1.5359x over previous
//
#include <hip/hip_runtime.h>
#include <hip/hip_bf16.h>

#define T_TOKENS 8192
#define H_DIM    1024

typedef __bf16 bf16x8 __attribute__((ext_vector_type(8)));
typedef float  f32x4  __attribute__((ext_vector_type(4)));

__device__ __forceinline__ unsigned short f2bf(float f) {
    union { float f; unsigned u; } v; v.f = f;
    unsigned r = v.u + 0x7FFFu + ((v.u >> 16) & 1u);
    return (unsigned short)(r >> 16);
}
__device__ __forceinline__ float bflo(unsigned w) { union { unsigned u; float f; } v; v.u = w << 16; return v.f; }
__device__ __forceinline__ float bfhi(unsigned w) { union { unsigned u; float f; } v; v.u = w & 0xFFFF0000u; return v.f; }

__device__ __forceinline__ void gload_lds16(const unsigned short* g, unsigned short* l) {
    __builtin_amdgcn_global_load_lds(
        (const __attribute__((address_space(1))) unsigned int*)g,
        (__attribute__((address_space(3))) unsigned int*)l, 16, 0, 0);
}

#define VMCNT(n) asm volatile("s_waitcnt vmcnt(" #n ")" ::: "memory")
#define BARR()   __builtin_amdgcn_s_barrier()
#define PRIO1    __builtin_amdgcn_s_setprio(1)
#define PRIO0    __builtin_amdgcn_s_setprio(0)

// ---------------- fused pre: wconv (bids 0..8191) + router (bids 8192..10239, 1 token/wave) ----------------
// Router geometry lesson (R7): router needs ~2048 blocks for TLP; 64-block serial-loop
// variant starved the machine (6% occupancy, 84us). No atomics here at all.
__global__ __launch_bounds__(256) void moe_pre(
    const float* __restrict__ x, const float* __restrict__ gw, const float* __restrict__ gb,
    const float* __restrict__ ew,
    float* __restrict__ logits, unsigned short* __restrict__ xb, unsigned short* __restrict__ wt,
    int* __restrict__ ridx, float* __restrict__ rp, int* __restrict__ cnt)
{
    __shared__ float smem[H_DIM * 9];
    int bid = blockIdx.x, tid = threadIdx.x;

    if (bid < 8192) {
        // ---- W transpose + bf16: Wt[e][n][k] = W[e][k][n], 32x32 tile ----
        int e = bid >> 10, rem = bid & 1023;
        int n0 = (rem & 31) << 5, k0 = (rem >> 5) << 5;
        int tx = tid & 31, ty = tid >> 5;
        const float* src = ew + ((size_t)e << 20) + (size_t)k0 * H_DIM + n0;
        #pragma unroll
        for (int i = 0; i < 4; ++i) smem[(ty + i*8) * 33 + tx] = src[(ty + i*8) * H_DIM + tx];
        __syncthreads();
        unsigned short* dst = wt + ((size_t)e << 20) + (size_t)n0 * H_DIM + k0;
        #pragma unroll
        for (int i = 0; i < 4; ++i) dst[(ty + i*8) * H_DIM + tx] = f2bf(smem[tx * 33 + ty + i*8]);
        return;
    }

    // ---- router: f32 logits, top-2, bf16 x (1 token per wave) ----
    int rb = bid - 8192;                  // 0..2047
    if (rb == 0 && tid < 8) cnt[tid] = 0; // zero counters for scatter (replaces memset launch)
    for (int i = tid; i < H_DIM; i += 256) {
        const float* s = gw + i * 8;
        float* d = smem + i * 9;
        #pragma unroll
        for (int e = 0; e < 8; ++e) d[e] = s[e];
    }
    __syncthreads();

    int wave = tid >> 6, lane = tid & 63;
    int t = rb * 4 + wave;

    float xl[16];
    const float* xrow = x + (size_t)t * H_DIM;
    #pragma unroll
    for (int q = 0; q < 16; ++q) xl[q] = xrow[lane + 64 * q];

    float acc[8] = {0,0,0,0,0,0,0,0};
    #pragma unroll
    for (int q = 0; q < 16; ++q) {
        float xv = xl[q];
        const float* g = &smem[(lane + 64 * q) * 9];
        #pragma unroll
        for (int e = 0; e < 8; ++e) acc[e] += xv * g[e];
    }
    #pragma unroll
    for (int e = 0; e < 8; ++e) {
        float v = acc[e];
        #pragma unroll
        for (int m = 32; m >= 1; m >>= 1) v += __shfl_xor(v, m, 64);
        acc[e] = v + gb[e];
    }
    if (lane == 0) {
        float* lrow = logits + (size_t)t * 8;
        #pragma unroll
        for (int e = 0; e < 8; ++e) lrow[e] = acc[e];
        int b0 = 0; float v0 = acc[0];
        #pragma unroll
        for (int e = 1; e < 8; ++e) if (acc[e] > v0) { v0 = acc[e]; b0 = e; }
        int b1 = -1; float v1 = -1e30f;
        #pragma unroll
        for (int e = 0; e < 8; ++e) if (e != b0 && acc[e] > v1) { v1 = acc[e]; b1 = e; }
        float ex = __expf(v1 - v0);
        float s = 1.0f / (1.0f + ex);
        ridx[2*t] = b0; ridx[2*t+1] = b1;
        rp[2*t] = s;    rp[2*t+1] = ex * s;
    }
    unsigned short* xbrow = xb + (size_t)t * H_DIM;
    #pragma unroll
    for (int q = 0; q < 16; ++q) xbrow[lane + 64 * q] = f2bf(xl[q]);
}

// ---------------- scatter: two-level (LDS hist -> 8 coalesced global atomics/block) ----------------
// 32 blocks x 256 threads, 1 token/thread. O(blocks) global RMW instructions (R6 lesson).
__global__ void moe_scatter(const int* __restrict__ ridx,
                            int* __restrict__ cnt, int* __restrict__ tlist, int* __restrict__ ppos) {
    __shared__ int loc[8];
    __shared__ int base[8];
    int tid = threadIdx.x;
    if (tid < 8) loc[tid] = 0;
    __syncthreads();
    int t = blockIdx.x * 256 + tid;
    int e0 = ridx[2*t], e1 = ridx[2*t+1];
    int l0 = atomicAdd(&loc[e0], 1);
    int l1 = atomicAdd(&loc[e1], 1);
    __syncthreads();
    if (tid < 8 && loc[tid]) base[tid] = atomicAdd(&cnt[tid], loc[tid]);
    __syncthreads();
    int p0 = base[e0] + l0, p1 = base[e1] + l1;
    tlist[(e0 << 13) + p0] = t; ppos[2*t]   = (e0 << 13) | p0;
    tlist[(e1 << 13) + p1] = t; ppos[2*t+1] = (e1 << 13) | p1;
}

// ---------------- grouped expert GEMM ----------------
// Main: 256x256x64, 8 waves, 4-phase counted-vmcnt, one round (<=256 tiles).
// Tail: 64x256x64 strips for per-expert remainder rows (<=128 tiles).
__global__ __launch_bounds__(512, 2) void moe_gemm(
    const unsigned short* __restrict__ xb, const unsigned short* __restrict__ wt,
    const int* __restrict__ cntg, const int* __restrict__ tlist, unsigned short* __restrict__ eout)
{
    __shared__ __align__(16) unsigned short lds[65536];

    int bid = blockIdx.x;
    int tid = threadIdx.x;
    int wv = tid >> 6, lane = tid & 63;
    int lane15 = lane & 15, q = lane >> 4, l7 = lane & 7;
    int c00 = ((q)     ^ l7) << 3;
    int c01 = ((4 + q) ^ l7) << 3;

    int cc[8];
    #pragma unroll
    for (int i = 0; i < 8; ++i) cc[i] = cntg[i];
    int totMB = 0;
    #pragma unroll
    for (int i = 0; i < 8; ++i) totMB += cc[i] >> 8;
    int nmain = totMB << 2;

    if (bid < nmain) {
        // -------- main: 256x256 --------
        int w0;
        if (nmain >= 8) {           // bijective XCD chunk swizzle (m204)
            int qq = nmain >> 3, r = nmain & 7;
            int xq = bid & 7, o = bid >> 3;
            w0 = (xq < r ? xq * (qq + 1) : r * (qq + 1) + (xq - r) * qq) + o;
        } else w0 = bid;
        int mb_lin = w0 >> 2, nb = w0 & 3;

        int e = 0, off = 0, cnt = 0, mbSel = 0;
        {
            int offR = 0, mbb = 0;
            #pragma unroll
            for (int i = 0; i < 8; ++i) {
                int fl = cc[i] >> 8;
                if (mb_lin >= mbb && mb_lin < mbb + fl) { e = i; off = offR; cnt = cc[i]; mbSel = mbb; }
                mbb += fl; offR += cc[i];
            }
        }
        int m0 = (mb_lin - mbSel) << 8;
        int n0 = nb << 8;
        int wm = wv >> 2, wn = wv & 3;

        const unsigned short* wte = wt + ((size_t)e << 20);
        const int* tle = tlist + (e << 13);

        const unsigned short* aP[2][2];
        const unsigned short* bP[2];
        int dA[2], dB[2];
        #pragma unroll
        for (int l = 0; l < 2; ++l) {
            int c = wv * 128 + l * 64 + lane;
            int r = c >> 3, s = c & 7;
            int col = (s ^ (r & 7)) << 3;
            int rowA = (r & 63) + ((r >> 6) << 7);
            int rowB = ((r >> 5) << 6) + (r & 31);
            dA[l] = rowA * 64 + s * 8;
            dB[l] = rowB * 64 + s * 8;
            int ma = m0 + rowA, mb2 = ma + 64;
            int t0 = tle[ma  < cnt ? ma  : cnt - 1];
            int t1 = tle[mb2 < cnt ? mb2 : cnt - 1];
            aP[l][0] = xb + (size_t)t0 * H_DIM + col;
            aP[l][1] = xb + (size_t)t1 * H_DIM + col;
            bP[l] = wte + (size_t)(n0 + rowB) * H_DIM + col;
        }

        unsigned short* A_ = lds;
        unsigned short* B_ = lds + 32768;

#define STG_A(MH, TT, NXT) do { \
    gload_lds16(aP[0][MH] + (TT)*64, A_ + (NXT)*16384 + dA[0] + (MH)*4096); \
    gload_lds16(aP[1][MH] + (TT)*64, A_ + (NXT)*16384 + dA[1] + (MH)*4096); } while(0)
#define STG_B(NH, TT, NXT) do { \
    gload_lds16(bP[0] + (NH)*32768 + (TT)*64, B_ + (NXT)*16384 + dB[0] + (NH)*2048); \
    gload_lds16(bP[1] + (NH)*32768 + (TT)*64, B_ + (NXT)*16384 + dB[1] + (NH)*2048); } while(0)

        const unsigned short* aR = A_ + (wm * 128 + lane15) * 64;
        const unsigned short* bR = B_ + (wn * 64 + lane15) * 64;

#define READ_A(MH, CU) do { _Pragma("unroll") \
    for (int iq = 0; iq < 4; ++iq) { \
        a[iq][0] = *(const bf16x8*)(aR + (CU)*16384 + (MH)*4096 + iq*1024 + c00); \
        a[iq][1] = *(const bf16x8*)(aR + (CU)*16384 + (MH)*4096 + iq*1024 + c01); } } while(0)
#define READ_B(NH, CU) do { _Pragma("unroll") \
    for (int jj = 0; jj < 2; ++jj) { \
        b[(NH)*2+jj][0] = *(const bf16x8*)(bR + (CU)*16384 + (NH)*2048 + jj*1024 + c00); \
        b[(NH)*2+jj][1] = *(const bf16x8*)(bR + (CU)*16384 + (NH)*2048 + jj*1024 + c01); } } while(0)

        f32x4 acc[8][4];
        #pragma unroll
        for (int i = 0; i < 8; ++i)
            #pragma unroll
            for (int j = 0; j < 4; ++j) acc[i][j] = (f32x4){0.f,0.f,0.f,0.f};

#define MM(MH, NH) do { _Pragma("unroll") \
    for (int iq = 0; iq < 4; ++iq) { _Pragma("unroll") \
        for (int jj = 0; jj < 2; ++jj) { \
            acc[(MH)*4+iq][(NH)*2+jj] = __builtin_amdgcn_mfma_f32_16x16x32_bf16(a[iq][0], b[(NH)*2+jj][0], acc[(MH)*4+iq][(NH)*2+jj], 0,0,0); \
            acc[(MH)*4+iq][(NH)*2+jj] = __builtin_amdgcn_mfma_f32_16x16x32_bf16(a[iq][1], b[(NH)*2+jj][1], acc[(MH)*4+iq][(NH)*2+jj], 0,0,0); } } } while(0)

        STG_A(0, 0, 0); STG_B(0, 0, 0); STG_B(1, 0, 0); STG_A(1, 0, 0);
        VMCNT(4);
        BARR();

        for (int t = 0; t < 15; ++t) {
            int cu = t & 1, nx = cu ^ 1, tn = t + 1;
            bf16x8 a[4][2]; bf16x8 b[4][2];
            READ_A(0, cu); READ_B(0, cu);
            STG_A(0, tn, nx);
            BARR(); PRIO1; MM(0, 0); PRIO0; VMCNT(4); BARR();
            READ_B(1, cu);
            STG_B(0, tn, nx);
            BARR(); PRIO1; MM(0, 1); PRIO0; VMCNT(4); BARR();
            READ_A(1, cu);
            STG_B(1, tn, nx);
            BARR(); PRIO1; MM(1, 1); PRIO0; BARR();
            STG_A(1, tn, nx);
            BARR(); PRIO1; MM(1, 0); PRIO0; VMCNT(4); BARR();
        }
        {
            bf16x8 a[4][2]; bf16x8 b[4][2];
            READ_A(0, 1); READ_B(0, 1);
            BARR(); PRIO1; MM(0, 0); PRIO0; VMCNT(2); BARR();
            READ_B(1, 1);
            BARR(); PRIO1; MM(0, 1); PRIO0; VMCNT(0); BARR();
            READ_A(1, 1);
            BARR(); PRIO1; MM(1, 1); PRIO0; BARR();
            PRIO1; MM(1, 0); PRIO0;
        }

        #pragma unroll
        for (int i = 0; i < 8; ++i) {
            #pragma unroll
            for (int rr = 0; rr < 4; ++rr) {
                int m = m0 + wm * 128 + i * 16 + (q << 2) + rr;
                if (m < cnt) {
                    unsigned short* erow = eout + (size_t)(off + m) * H_DIM + n0 + wn * 64 + lane15;
                    #pragma unroll
                    for (int j = 0; j < 4; ++j)
                        erow[j * 16] = f2bf(acc[i][j][rr]);
                }
            }
        }
        return;
#undef STG_A
#undef STG_B
#undef READ_A
#undef READ_B
#undef MM
    }

    // -------- tail: 64x256 strips over remainder rows --------
    int w1 = bid - nmain;
    int totTB = 0;
    #pragma unroll
    for (int i = 0; i < 8; ++i) { int fl = cc[i] >> 8; totTB += ((cc[i] - (fl << 8)) + 63) >> 6; }
    if (w1 >= totTB * 4) return;
    int s_lin = w1 >> 2, nb = w1 & 3;

    int e = 0, off = 0, cnt = 0, tbSel = 0, flSel = 0;
    {
        int offR = 0, tbb = 0;
        #pragma unroll
        for (int i = 0; i < 8; ++i) {
            int fl = cc[i] >> 8;
            int ts = ((cc[i] - (fl << 8)) + 63) >> 6;
            if (s_lin >= tbb && s_lin < tbb + ts) { e = i; off = offR; cnt = cc[i]; tbSel = tbb; flSel = fl; }
            tbb += ts; offR += cc[i];
        }
    }
    int m0 = (flSel << 8) + ((s_lin - tbSel) << 6);
    int n0 = nb << 8;
    int wm2 = wv >> 2, wn = wv & 3;

    const unsigned short* wte = wt + ((size_t)e << 20);
    const int* tle = tlist + (e << 13);

    int rA = tid >> 3, sA = tid & 7;
    int colA = (sA ^ (rA & 7)) << 3;
    int ma = m0 + rA;
    const unsigned short* aP = xb + (size_t)tle[ma < cnt ? ma : cnt - 1] * H_DIM + colA;
    int dAt = rA * 64 + sA * 8;

    const unsigned short* bP[2];
    int dB[2];
    #pragma unroll
    for (int l = 0; l < 2; ++l) {
        int c = wv * 128 + l * 64 + lane;
        int r = c >> 3, s = c & 7;
        int col = (s ^ (r & 7)) << 3;
        int rowB = ((r >> 5) << 6) + (r & 31);
        dB[l] = rowB * 64 + s * 8;
        bP[l] = wte + (size_t)(n0 + rowB) * H_DIM + col;
    }

    unsigned short* A_ = lds;
    unsigned short* B_ = lds + 8192;

    const unsigned short* aR = A_ + (wm2 * 32 + lane15) * 64;
    const unsigned short* bR = B_ + (wn * 64 + lane15) * 64;

#define TSTG_A(TT, NXT) gload_lds16(aP + (TT)*64, A_ + (NXT)*4096 + dAt)
#define TSTG_B(NH, TT, NXT) do { \
    gload_lds16(bP[0] + (NH)*32768 + (TT)*64, B_ + (NXT)*16384 + dB[0] + (NH)*2048); \
    gload_lds16(bP[1] + (NH)*32768 + (TT)*64, B_ + (NXT)*16384 + dB[1] + (NH)*2048); } while(0)
#define TREAD_A(CU) do { _Pragma("unroll") \
    for (int iq = 0; iq < 2; ++iq) { \
        a[iq][0] = *(const bf16x8*)(aR + (CU)*4096 + iq*1024 + c00); \
        a[iq][1] = *(const bf16x8*)(aR + (CU)*4096 + iq*1024 + c01); } } while(0)
#define TREAD_B(NH, CU) do { _Pragma("unroll") \
    for (int jj = 0; jj < 2; ++jj) { \
        b[(NH)*2+jj][0] = *(const bf16x8*)(bR + (CU)*16384 + (NH)*2048 + jj*1024 + c00); \
        b[(NH)*2+jj][1] = *(const bf16x8*)(bR + (CU)*16384 + (NH)*2048 + jj*1024 + c01); } } while(0)
#define TMM(NH) do { _Pragma("unroll") \
    for (int iq = 0; iq < 2; ++iq) { _Pragma("unroll") \
        for (int jj = 0; jj < 2; ++jj) { \
            acc[iq][(NH)*2+jj] = __builtin_amdgcn_mfma_f32_16x16x32_bf16(a[iq][0], b[(NH)*2+jj][0], acc[iq][(NH)*2+jj], 0,0,0); \
            acc[iq][(NH)*2+jj] = __builtin_amdgcn_mfma_f32_16x16x32_bf16(a[iq][1], b[(NH)*2+jj][1], acc[iq][(NH)*2+jj], 0,0,0); } } } while(0)

    f32x4 acc[2][4];
    #pragma unroll
    for (int i = 0; i < 2; ++i)
        #pragma unroll
        for (int j = 0; j < 4; ++j) acc[i][j] = (f32x4){0.f,0.f,0.f,0.f};

    TSTG_A(0, 0); TSTG_B(0, 0, 0); TSTG_B(1, 0, 0);
    VMCNT(2); BARR();

    for (int t = 0; t < 15; ++t) {
        int cu = t & 1, nx = cu ^ 1, tn = t + 1;
        bf16x8 a[2][2]; bf16x8 b[4][2];
        TREAD_A(cu); TREAD_B(0, cu);
        TSTG_A(tn, nx); TSTG_B(0, tn, nx);
        BARR(); PRIO1; TMM(0); PRIO0; VMCNT(3); BARR();
        TREAD_B(1, cu);
        TSTG_B(1, tn, nx);
        BARR(); PRIO1; TMM(1); PRIO0; VMCNT(2); BARR();
    }
    {
        bf16x8 a[2][2]; bf16x8 b[4][2];
        TREAD_A(1); TREAD_B(0, 1);
        BARR(); PRIO1; TMM(0); PRIO0; VMCNT(0); BARR();
        TREAD_B(1, 1);
        BARR(); PRIO1; TMM(1); PRIO0;
    }

    #pragma unroll
    for (int iq = 0; iq < 2; ++iq) {
        #pragma unroll
        for (int rr = 0; rr < 4; ++rr) {
            int m = m0 + wm2 * 32 + iq * 16 + (q << 2) + rr;
            if (m < cnt) {
                unsigned short* erow = eout + (size_t)(off + m) * H_DIM + n0 + wn * 64 + lane15;
                #pragma unroll
                for (int j = 0; j < 4; ++j)
                    erow[j * 16] = f2bf(acc[iq][j][rr]);
            }
        }
    }
#undef TSTG_A
#undef TSTG_B
#undef TREAD_A
#undef TREAD_B
#undef TMM
}

// ---------------- combine: out[t] = p0*(v0 + b_e0) + p1*(v1 + b_e1) ----------------
__global__ __launch_bounds__(256) void moe_combine(
    const float* __restrict__ rp, const int* __restrict__ ppos, const int* __restrict__ cntg,
    const unsigned short* __restrict__ eout, const float* __restrict__ eb, float* __restrict__ out)
{
    __shared__ int offsS[8];
    if (threadIdx.x == 0) {
        int s = 0;
        #pragma unroll
        for (int i = 0; i < 8; ++i) { offsS[i] = s; s += cntg[i]; }
    }
    __syncthreads();
    int idx = blockIdx.x * 256 + threadIdx.x;
    int t = idx >> 7, c = (idx & 127) << 3;
    int u0 = ppos[2*t], u1 = ppos[2*t+1];
    int e0 = u0 >> 13, e1 = u1 >> 13;
    int s0 = offsS[e0] + (u0 & 8191);
    int s1 = offsS[e1] + (u1 & 8191);
    float p0 = rp[2*t], p1 = rp[2*t+1];
    uint4 v0 = *(const uint4*)(eout + (size_t)s0 * H_DIM + c);
    uint4 v1 = *(const uint4*)(eout + (size_t)s1 * H_DIM + c);
    const float* b0 = eb + e0 * H_DIM + c;
    const float* b1 = eb + e1 * H_DIM + c;
    float r[8];
    const unsigned* w0 = &v0.x;
    const unsigned* w1 = &v1.x;
    #pragma unroll
    for (int k = 0; k < 4; ++k) {
        r[2*k]   = p0 * (bflo(w0[k]) + b0[2*k])   + p1 * (bflo(w1[k]) + b1[2*k]);
        r[2*k+1] = p0 * (bfhi(w0[k]) + b0[2*k+1]) + p1 * (bfhi(w1[k]) + b1[2*k+1]);
    }
    float4* op = (float4*)(out + (size_t)t * H_DIM + c);
    op[0] = make_float4(r[0], r[1], r[2], r[3]);
    op[1] = make_float4(r[4], r[5], r[6], r[7]);
}

extern "C" void kernel_launch(void* const* d_in, const int* in_sizes, int n_in,
                              void* d_out, int out_size, void* d_ws, size_t ws_size,
                              hipStream_t stream) {
    const float* x  = (const float*)d_in[0];
    const float* gw = (const float*)d_in[1];
    const float* gb = (const float*)d_in[2];
    const float* ew = (const float*)d_in[3];
    const float* eb = (const float*)d_in[4];

    float* out    = (float*)d_out;
    float* logits = out + (size_t)T_TOKENS * H_DIM;

    char* ws = (char*)d_ws;
    unsigned short* xb   = (unsigned short*)(ws);                       // 16 MiB
    unsigned short* wt   = (unsigned short*)(ws + 16777216);            // 16 MiB
    unsigned short* eout = (unsigned short*)(ws + 33554432);            // 32 MiB
    int*   tlist   = (int*)  (ws + 67108864);                           // 256 KiB (8 x 8192)
    float* rp      = (float*)(ws + 67371008);                           // 64 KiB
    int*   ppos    = (int*)  (ws + 67436544);                           // 64 KiB
    int*   ridx    = (int*)  (ws + 67502080);                           // 64 KiB
    int*   cnt     = (int*)  (ws + 67567616);                           // 8 ints

    moe_pre    <<<10240, 256, 0, stream>>>(x, gw, gb, ew, logits, xb, wt, ridx, rp, cnt);
    moe_scatter<<<T_TOKENS/256, 256, 0, stream>>>(ridx, cnt, tlist, ppos);
    moe_gemm   <<<384, 512, 0, stream>>>(xb, wt, cnt, tlist, eout);
    moe_combine<<<(T_TOKENS*H_DIM/8)/256, 256, 0, stream>>>(rp, ppos, cnt, eout, eb, out);
}